// Round 13
// baseline (337.681 us; speedup 1.0000x reference)
//
#include <hip/hip_runtime.h>
#include <hip/hip_bf16.h>
#include <math.h>

// Problem constants (from reference)
#define B_SZ   128
#define HDIM   256
#define NG     1280     // 5*H
#define NNODES 1023
#define VOCAB  2048

typedef unsigned int uint32;
typedef short  short8v  __attribute__((ext_vector_type(8)));   // 8 x bf16 (4 VGPR)
typedef float  float4v  __attribute__((ext_vector_type(4)));   // MFMA C/D frag

__device__ __forceinline__ float sigm(float x) {
    return 1.0f / (1.0f + __expf(-x));
}
__device__ __forceinline__ float tanh_fast(float x) {
    return 2.0f / (1.0f + __expf(-2.0f * x)) - 1.0f;
}
__device__ __forceinline__ float bf2f(unsigned short u) {
    return __uint_as_float(((uint32)u) << 16);
}
__device__ __forceinline__ unsigned short f2bf(float f) {
    uint32 x = __float_as_uint(f);
    uint32 r = (x + 0x7FFFu + ((x >> 16) & 1u)) >> 16;   // RNE
    return (unsigned short)r;
}

// Async 16B/lane global->LDS DMA. LDS dest = wave-uniform base + lane*16.
__device__ __forceinline__ void dma16(const unsigned short* gptr, unsigned short* lptr) {
    __builtin_amdgcn_global_load_lds(
        (const __attribute__((address_space(1))) void*)gptr,
        (__attribute__((address_space(3))) void*)lptr, 16, 0, 0);
}

// ---------------------------------------------------------------------------
// embb = bf16(emb) : 2048 x 256.  A-operand for the table builders + levels' x.
// ---------------------------------------------------------------------------
__global__ __launch_bounds__(256) void embb_kernel(
    const float* __restrict__ emb, unsigned short* __restrict__ embb)
{
    const int t = blockIdx.x * 256 + threadIdx.x;
    const float4 v0 = *(const float4*)(emb + (size_t)t * 8);
    const float4 v1 = *(const float4*)(emb + (size_t)t * 8 + 4);
    short8v o;
    o[0] = (short)f2bf(v0.x); o[1] = (short)f2bf(v0.y);
    o[2] = (short)f2bf(v0.z); o[3] = (short)f2bf(v0.w);
    o[4] = (short)f2bf(v1.x); o[5] = (short)f2bf(v1.y);
    o[6] = (short)f2bf(v1.z); o[7] = (short)f2bf(v1.w);
    *(short8v*)(embb + (size_t)t * 8) = o;
}

// ---------------------------------------------------------------------------
// WTf: fragment-ready bf16 repack of [Ul;Ur;Wx] (K=768, N=1280) for MFMA B.
// short8 index = (ng*24 + ks)*64 + lane ; lane = q*16 + c
//   holds B[k = ks*32 + q*8 + j][col = ng*16 + c],  j = 0..7
// Fold levels use all 24 ks; table builders use ks_base 0 (Ul), 8 (Ur),
// 16 (Wx) with 8 ks each (K=256).
// ---------------------------------------------------------------------------
__global__ __launch_bounds__(256) void prep_wtf(
    const float* __restrict__ Ul, const float* __restrict__ Ur,
    const float* __restrict__ Wx, unsigned short* __restrict__ WTf)
{
    const int t = blockIdx.x * 256 + threadIdx.x;   // 0..122879
    const int l = t & 63;
    const int q = l >> 4, c = l & 15;
    const int ks = (t >> 6) % 24;
    const int ng = t / (24 * 64);                    // 0..79
    const int col = ng * 16 + c;
    const int k = ks * 32 + q * 8;
    const float* src = (k < 256) ? (Ul + (size_t)k * NG + col)
                     : (k < 512) ? (Ur + (size_t)(k - 256) * NG + col)
                                 : (Wx + (size_t)(k - 512) * NG + col);
    short8v v;
    #pragma unroll
    for (int j = 0; j < 8; ++j) v[j] = (short)f2bf(src[(size_t)j * NG]);
    *(short8v*)(WTf + (size_t)t * 8) = v;
}

// ---------------------------------------------------------------------------
// gemm_tab: O[2048][1280] = bf16( A(2048x256) @ Wsec(256x1280) [+ bias] ).
// Wsec = ks_base0 + 8*blockIdx.z (0=Ul, 8=Ur, 16=Wx); O = z ? O1 : O0 --
// the two HU builds run as ONE launch with gridDim.z=2.  TAB=true also
// computes the leaf h/c tables in-epilogue from acc (absorbs leaftab).
// ---------------------------------------------------------------------------
template <bool TAB>
__global__ __launch_bounds__(256, 2) void gemm_tab(
    const unsigned short* __restrict__ WTf, const unsigned short* __restrict__ A,
    const float* __restrict__ bias, unsigned short* __restrict__ O0,
    unsigned short* __restrict__ O1,
    unsigned short* __restrict__ Hleaf, unsigned short* __restrict__ Cleaf,
    const int ks_base0)
{
    __shared__ __align__(16) unsigned short Ab[2][4096];   // 16 KB A dbuf
    __shared__ __align__(16) unsigned short wbE[20480];    // 40 KB: 5 gates x 64 rows x 64 cols

    const int tid  = threadIdx.x;
    const int lane = tid & 63;
    const int w    = tid >> 6;                  // 0..3 = col-tile
    const int quad = lane >> 4, col15 = lane & 15;
    const int jt = blockIdx.x;
    const int rowBase = blockIdx.y * 64;        // A row
    const int jbase   = jt * 64;
    const int ks_base = ks_base0 + (int)blockIdx.z * 8;
    unsigned short* O = blockIdx.z ? O1 : O0;

    const unsigned short* agp[2];
    unsigned short* ldst[2];
    #pragma unroll
    for (int t = 0; t < 2; ++t) {
        const int ch = 2 * w + t, sub = ch >> 2, rt = ch & 3;
        const int srow = rowBase + rt * 16 + col15;
        agp[t]  = A + (size_t)srow * HDIM + sub * 32 + quad * 8;
        ldst[t] = &Ab[0][0] + ch * 512;
    }

    const short8v* WTfv = (const short8v*)WTf;
    uint32 boff[5];
    #pragma unroll
    for (int g = 0; g < 5; ++g)
        boff[g] = (uint32)(((g * 16 + jt * 4 + w) * 24 + ks_base) * 64 + lane);

    float4v acc[4][5];
    #pragma unroll
    for (int rt = 0; rt < 4; ++rt)
        #pragma unroll
        for (int g = 0; g < 5; ++g)
            #pragma unroll
            for (int e = 0; e < 4; ++e) acc[rt][g][e] = 0.0f;

    dma16(agp[0], ldst[0]); dma16(agp[1], ldst[1]);
    __syncthreads();

    #pragma unroll
    for (int s = 0; s < 4; ++s) {
        if (s < 3) {
            dma16(agp[0] + (s + 1) * 64, ldst[0] + ((s + 1) & 1) * 4096);
            dma16(agp[1] + (s + 1) * 64, ldst[1] + ((s + 1) & 1) * 4096);
        }
        #pragma unroll
        for (int sub = 0; sub < 2; ++sub) {
            short8v bf[5];
            #pragma unroll
            for (int g = 0; g < 5; ++g) bf[g] = WTfv[boff[g] + (s * 2 + sub) * 64];
            #pragma unroll
            for (int rt = 0; rt < 4; ++rt) {
                const short8v af = *(const short8v*)&Ab[s & 1][(sub * 4 + rt) * 512 + lane * 8];
                #pragma unroll
                for (int g = 0; g < 5; ++g)
                    acc[rt][g] = __builtin_amdgcn_mfma_f32_16x16x32_bf16(
                        af, bf[g], acc[rt][g], 0, 0, 0);
            }
        }
        __syncthreads();
    }

    const int jl = w * 16 + col15;
    const int j  = jbase + jl;
    float bz[5];
    #pragma unroll
    for (int g = 0; g < 5; ++g) bz[g] = bias ? bias[g * 256 + j] : 0.0f;
    const int jchunk = jl >> 3, jpos = jl & 7;

    if (TAB) {
        // Leaf h/c tables directly from acc (gi=g0, go=g3, gu=g4).
        #pragma unroll
        for (int rt = 0; rt < 4; ++rt) {
            #pragma unroll
            for (int reg = 0; reg < 4; ++reg) {
                const int rr = rt * 16 + quad * 4 + reg;
                const float gi = acc[rt][0][reg] + bz[0];
                const float go = acc[rt][3][reg] + bz[3];
                const float gu = acc[rt][4][reg] + bz[4];
                const float c = sigm(gi) * tanh_fast(gu);
                const float h = sigm(go) * tanh_fast(c);
                Hleaf[(size_t)(rowBase + rr) * HDIM + j] = f2bf(h);
                Cleaf[(size_t)(rowBase + rr) * HDIM + j] = f2bf(c);
            }
        }
    }

    #pragma unroll
    for (int rt = 0; rt < 4; ++rt) {
        #pragma unroll
        for (int reg = 0; reg < 4; ++reg) {
            const int rr = rt * 16 + quad * 4 + reg;
            const int roff = ((jchunk + 2 * quad) & 7) * 8 + jpos;  // (rr>>2)&3==quad
            #pragma unroll
            for (int g = 0; g < 5; ++g)
                wbE[(g * 64 + rr) * 64 + roff] = f2bf(acc[rt][g][reg] + bz[g]);
        }
    }
    __syncthreads();

    #pragma unroll
    for (int k2 = 0; k2 < 10; ++k2) {
        const int c = tid + k2 * 256;                // 0..2559
        const int g = c >> 9, rr = (c >> 3) & 63, u = c & 7;
        const int ru = (u + 2 * ((rr >> 2) & 3)) & 7;
        const short8v v = *(const short8v*)&wbE[(g * 64 + rr) * 64 + ru * 8];
        *(short8v*)(O + (size_t)(rowBase + rr) * NG + g * 256 + jbase + u * 8) = v;
    }
}

// ---------------------------------------------------------------------------
// leafcell: level d=8 WITHOUT a GEMM.  gates = HUl[tokL] + HUr[tokR] +
// EWb[tokN] (bias inside EWb) -> LSTM cell with cl/cr from Cleaf.
// ---------------------------------------------------------------------------
__global__ __launch_bounds__(256) void leafcell_kernel(
    const int* __restrict__ tokens,
    const unsigned short* __restrict__ HUl, const unsigned short* __restrict__ HUr,
    const unsigned short* __restrict__ EWb, const unsigned short* __restrict__ Cleaf,
    unsigned short* __restrict__ hdst, unsigned short* __restrict__ cdst)
{
    const int t = blockIdx.x * 256 + threadIdx.x;   // 0..1048575
    const int row = t >> 5;                          // 0..32767 = b*256 + i
    const int j   = (t & 31) * 8;                    // h-col octet
    const int b = row >> 8, i = row & 255;
    const int tokN = tokens[b * NNODES + 255 + i];
    const int tokL = tokens[b * NNODES + 511 + 2 * i];
    const int tokR = tokens[b * NNODES + 512 + 2 * i];

    const unsigned short* pl = HUl + (size_t)tokL * NG + j;
    const unsigned short* pr = HUr + (size_t)tokR * NG + j;
    const unsigned short* pn = EWb + (size_t)tokN * NG + j;

    float g5[5][8];
    #pragma unroll
    for (int g = 0; g < 5; ++g) {
        const short8v vl = *(const short8v*)(pl + g * 256);
        const short8v vr = *(const short8v*)(pr + g * 256);
        const short8v vn = *(const short8v*)(pn + g * 256);
        #pragma unroll
        for (int e = 0; e < 8; ++e)
            g5[g][e] = bf2f((unsigned short)vl[e]) + bf2f((unsigned short)vr[e])
                     + bf2f((unsigned short)vn[e]);
    }
    const short8v cl8 = *(const short8v*)(Cleaf + (size_t)tokL * HDIM + j);
    const short8v cr8 = *(const short8v*)(Cleaf + (size_t)tokR * HDIM + j);

    short8v ho, co;
    #pragma unroll
    for (int e = 0; e < 8; ++e) {
        const float ii = sigm(g5[0][e]), fl = sigm(g5[1][e]);
        const float fr = sigm(g5[2][e]), oo = sigm(g5[3][e]);
        const float uu = tanh_fast(g5[4][e]);
        const float c = ii * uu + fl * bf2f((unsigned short)cl8[e])
                                + fr * bf2f((unsigned short)cr8[e]);
        const float h = oo * tanh_fast(c);
        co[e] = (short)f2bf(c);
        ho[e] = (short)f2bf(h);
    }
    *(short8v*)(hdst + (size_t)row * HDIM + j) = ho;
    *(short8v*)(cdst + (size_t)row * HDIM + j) = co;
}

// ---------------------------------------------------------------------------
// Levels d=7..0: K=768 fold [hl|hr|x]@[Ul;Ur;Wx], BK=128 (6 steps), bias
// hoisted.  Block-id swizzle (R10, now COMPILE-TIME -- R11): SWZ=true ->
// jt=(L>>3)&3, rowTile=(L>>5)*8+(L&7).
//   - jt-mates have ids {base, base+8, +16, +24}: same id mod 8 -> SAME XCD
//     (shared child rows hit that XCD's L2: d=7 FETCH 52->34 MB), AND within
//     a 32-id window -> CONCURRENT (d=7 77.5->59.6 us vs R9's rows-fastest).
//   - 8 consecutive rows spread across 8 XCDs (balanced).
// R11: SWZ is a template param, not a runtime gridDim branch -- the branch
// cost VGPR 96->112 in R10 and the tail levels regressed ~29 us.  SWZ=true
// for d>=2 (grid>=32, bijective); SWZ=false for d<=1 (jt-fastest).
// ---------------------------------------------------------------------------
template <bool SWZ>
__global__ __launch_bounds__(256, 2) void level_fold(
    const unsigned short* __restrict__ WTf, const int* __restrict__ tokens,
    const unsigned short* __restrict__ embb,
    const unsigned short* __restrict__ hsrc, const unsigned short* __restrict__ csrc,
    const float* __restrict__ bias,
    unsigned short* __restrict__ hdst, unsigned short* __restrict__ cdst,
    float* __restrict__ out, const int d)
{
    const int n = 1 << d;

    __shared__ __align__(16) unsigned short Ab[2][8192];   // 32 KB: dbuf 64r x 128k

    const int tid  = threadIdx.x;
    const int lane = tid & 63;
    const int w    = tid >> 6;
    const int quad = lane >> 4, col15 = lane & 15;

    const int L = blockIdx.x;
    const int jt      = SWZ ? ((L >> 3) & 3)            : (L & 3);
    const int rowTile = SWZ ? ((L >> 5) * 8 + (L & 7))  : (L >> 2);
    const int rowBase = rowTile * 64;
    const int jbase   = jt * 64;

    const uint32 inrow = (uint32)(w * 64 + quad * 16);
    uint32 oL[4], oR[4], oN[4];
    #pragma unroll
    for (int t = 0; t < 4; ++t) {
        const int srow = rowBase + t * 16 + col15;
        const int b = srow >> d, i = srow & (n - 1);
        oN[t] = (uint32)tokens[b * NNODES + (n - 1) + i] * 512u + inrow;
        oL[t] = (uint32)(2 * srow) * 512u + inrow;
        oR[t] = oL[t] + 512u;
    }
    const char* hb = (const char*)hsrc;
    const char* xb = (const char*)embb;

    const short8v* WTfv = (const short8v*)WTf;
    uint32 boff[5];
    #pragma unroll
    for (int g = 0; g < 5; ++g)
        boff[g] = ((g * 16 + jt * 4 + w) * 24) * 64 + lane;   // full K=768

    const int jl = w * 16 + col15;
    const int j  = jbase + jl;
    float bz[5];
    #pragma unroll
    for (int g = 0; g < 5; ++g) bz[g] = bias[g * 256 + j];

    float4v acc[4][5];
    #pragma unroll
    for (int rt = 0; rt < 4; ++rt)
        #pragma unroll
        for (int g = 0; g < 5; ++g)
            #pragma unroll
            for (int e = 0; e < 4; ++e) acc[rt][g][e] = 0.0f;

    {
        unsigned short* dst = &Ab[0][0] + w * 2048;
        #pragma unroll
        for (int t = 0; t < 4; ++t)
            dma16((const unsigned short*)(hb + oL[t]), dst + t * 512);
    }
    __syncthreads();

    #pragma unroll
    for (int s = 0; s < 6; ++s) {
        if (s < 5) {
            const int sn = s + 1;
            unsigned short* dst = &Ab[sn & 1][0] + w * 2048;
            #pragma unroll
            for (int t = 0; t < 4; ++t) {
                const char* p = (sn < 2) ? (hb + oL[t] + sn * 256)
                              : (sn < 4) ? (hb + oR[t] + (sn - 2) * 256)
                                         : (xb + oN[t] + (sn - 4) * 256);
                dma16((const unsigned short*)p, dst + t * 512);
            }
        }
        #pragma unroll
        for (int sub = 0; sub < 4; ++sub) {
            short8v bf[5];
            #pragma unroll
            for (int g = 0; g < 5; ++g) bf[g] = WTfv[boff[g] + (s * 4 + sub) * 64];
            #pragma unroll
            for (int rt = 0; rt < 4; ++rt) {
                const short8v af = *(const short8v*)&Ab[s & 1][(sub * 4 + rt) * 512 + lane * 8];
                #pragma unroll
                for (int g = 0; g < 5; ++g)
                    acc[rt][g] = __builtin_amdgcn_mfma_f32_16x16x32_bf16(
                        af, bf[g], acc[rt][g], 0, 0, 0);
            }
        }
        __syncthreads();
    }

    float hv[4][4], cv[4][4];
    #pragma unroll
    for (int rt = 0; rt < 4; ++rt) {
        #pragma unroll
        for (int reg = 0; reg < 4; ++reg) {
            const int rr = rt * 16 + quad * 4 + reg;
            const int grow = rowBase + rr;
            const float cl = bf2f(csrc[(size_t)(2 * grow) * HDIM + j]);
            const float cr = bf2f(csrc[(size_t)(2 * grow + 1) * HDIM + j]);
            const float gi  = acc[rt][0][reg] + bz[0];
            const float gfl = acc[rt][1][reg] + bz[1];
            const float gfr = acc[rt][2][reg] + bz[2];
            const float go  = acc[rt][3][reg] + bz[3];
            const float gu  = acc[rt][4][reg] + bz[4];
            const float ii = sigm(gi), fl = sigm(gfl), fr = sigm(gfr), oo = sigm(go);
            const float uu = tanh_fast(gu);
            const float c = ii * uu + fl * cl + fr * cr;
            const float h = oo * tanh_fast(c);
            cv[rt][reg] = c; hv[rt][reg] = h;
            if (d == 0) out[(size_t)grow * HDIM + j] = h;  // n==1 -> b=row
        }
    }
    if (d == 0) return;   // root level: nothing reads hdst/cdst

    unsigned short* wb = &Ab[0][0];
    const int jchunk = jl >> 3, jpos = jl & 7;
    #pragma unroll
    for (int rt = 0; rt < 4; ++rt) {
        #pragma unroll
        for (int reg = 0; reg < 4; ++reg) {
            const int rr = rt * 16 + quad * 4 + reg;
            const int roff = ((jchunk + 2 * quad) & 7) * 8 + jpos;
            wb[rr * 64 + roff]        = f2bf(hv[rt][reg]);
            wb[4096 + rr * 64 + roff] = f2bf(cv[rt][reg]);
        }
    }
    __syncthreads();
    #pragma unroll
    for (int k2 = 0; k2 < 4; ++k2) {
        const int c = tid + k2 * 256;
        const int arr = c >> 9, rr = (c >> 3) & 63, u = c & 7;
        const int ru = (u + 2 * ((rr >> 2) & 3)) & 7;
        const short8v v = *(const short8v*)(wb + (arr * 4096 + rr * 64 + ru * 8));
        unsigned short* dstp = (arr ? cdst : hdst) +
            (size_t)(rowBase + rr) * HDIM + jbase + u * 8;
        *(short8v*)dstp = v;
    }
}

// ---------------------------------------------------------------------------
extern "C" void kernel_launch(void* const* d_in, const int* in_sizes, int n_in,
                              void* d_out, int out_size, void* d_ws, size_t ws_size,
                              hipStream_t stream)
{
    const int*   tokens = (const int*)d_in[0];
    const float* emb    = (const float*)d_in[1];
    const float* Wx     = (const float*)d_in[2];
    const float* Ul     = (const float*)d_in[3];
    const float* Ur     = (const float*)d_in[4];
    const float* bias   = (const float*)d_in[5];
    float* out = (float*)d_out;

    // Workspace (bf16): EWb 5.24 | HUl 5.24 | HUr 5.24 | embb 1.05 | WTf 1.97
    // | Hleaf+Cleaf 2.1 | hA,cA 2x8.4 | hB,cB 2x16.8  -> ~70 MB total.
    const size_t EW_ELEMS  = (size_t)VOCAB * NG;          // also HUl/HUr size
    const size_t EMB_ELEMS = (size_t)VOCAB * HDIM;
    const size_t WTF_ELEMS = (size_t)80 * 24 * 64 * 8;
    const size_t LT_ELEMS  = (size_t)VOCAB * HDIM;        // each of Hleaf, Cleaf
    const size_t SLOT_A    = (size_t)16384 * HDIM;        // d=7,5,3,1 outputs
    const size_t SLOT_B    = (size_t)32768 * HDIM;        // d=8,6,4,2,0 outputs
    const size_t REQUIRED  = (3 * EW_ELEMS + EMB_ELEMS + WTF_ELEMS + 2 * LT_ELEMS
                              + 2 * (SLOT_A + SLOT_B)) * 2;
    if (ws_size < REQUIRED || d_ws == nullptr) return;   // clean fail, not a fault

    char* ws = (char*)d_ws;
    unsigned short* EWb   = (unsigned short*)ws;
    unsigned short* HUl   = EWb + EW_ELEMS;
    unsigned short* HUr   = HUl + EW_ELEMS;
    unsigned short* embb  = HUr + EW_ELEMS;
    unsigned short* WTf   = embb + EMB_ELEMS;
    unsigned short* Hleaf = WTf + WTF_ELEMS;
    unsigned short* Cleaf = Hleaf + LT_ELEMS;
    unsigned short* hA    = Cleaf + LT_ELEMS;
    unsigned short* cA    = hA + SLOT_A;
    unsigned short* hB    = cA + SLOT_A;
    unsigned short* cB    = hB + SLOT_B;

    embb_kernel<<<dim3(256), 256, 0, stream>>>(emb, embb);
    prep_wtf<<<dim3(480), 256, 0, stream>>>(Ul, Ur, Wx, WTf);
    // EWb = x@Wx + b, with leaf h/c tables fused into the epilogue.
    gemm_tab<true><<<dim3(4, 32, 1), 256, 0, stream>>>(
        WTf, embb, bias, EWb, nullptr, Hleaf, Cleaf, 16);
    // HUl = Hleaf@Ul and HUr = Hleaf@Ur in ONE launch (z selects section).
    gemm_tab<false><<<dim3(4, 32, 2), 256, 0, stream>>>(
        WTf, Hleaf, nullptr, HUl, HUr, nullptr, nullptr, 0);

    // Level d=8: pure table gather + cell (no GEMM).  Writes B-slot.
    leafcell_kernel<<<dim3(4096), 256, 0, stream>>>(
        tokens, HUl, HUr, EWb, Cleaf, hB, cB);

    // Levels d=7..0: fold variant; compile-time co-XCD+concurrent swizzle
    // for d>=2 (grid>=32), plain jt-fastest for the tiny d<=1 grids.
    for (int d = 7; d >= 0; --d) {
        const int NRB = 2 << d;
        const bool evenD = ((d & 1) == 0);
        const unsigned short* hs = evenD ? hA : hB;
        const unsigned short* cs = evenD ? cA : cB;
        unsigned short* hd = evenD ? hB : hA;
        unsigned short* cd = evenD ? cB : cA;
        if (d >= 2) {
            level_fold<true><<<dim3(4 * NRB), 256, 0, stream>>>(
                WTf, tokens, embb, hs, cs, bias, hd, cd, out, d);
        } else {
            level_fold<false><<<dim3(4 * NRB), 256, 0, stream>>>(
                WTf, tokens, embb, hs, cs, bias, hd, cd, out, d);
        }
    }
}

// Round 14
// 327.796 us; speedup vs baseline: 1.0302x; 1.0302x over previous
//
#include <hip/hip_runtime.h>
#include <hip/hip_bf16.h>
#include <math.h>

// Problem constants (from reference)
#define B_SZ   128
#define HDIM   256
#define NG     1280     // 5*H
#define NNODES 1023
#define VOCAB  2048

typedef unsigned int uint32;
typedef short  short8v  __attribute__((ext_vector_type(8)));   // 8 x bf16 (4 VGPR)
typedef float  float4v  __attribute__((ext_vector_type(4)));   // MFMA C/D frag

__device__ __forceinline__ float sigm(float x) {
    return 1.0f / (1.0f + __expf(-x));
}
__device__ __forceinline__ float tanh_fast(float x) {
    return 2.0f / (1.0f + __expf(-2.0f * x)) - 1.0f;
}
__device__ __forceinline__ float bf2f(unsigned short u) {
    return __uint_as_float(((uint32)u) << 16);
}
__device__ __forceinline__ unsigned short f2bf(float f) {
    uint32 x = __float_as_uint(f);
    uint32 r = (x + 0x7FFFu + ((x >> 16) & 1u)) >> 16;   // RNE
    return (unsigned short)r;
}

// Async 16B/lane global->LDS DMA. LDS dest = wave-uniform base + lane*16.
__device__ __forceinline__ void dma16(const unsigned short* gptr, unsigned short* lptr) {
    __builtin_amdgcn_global_load_lds(
        (const __attribute__((address_space(1))) void*)gptr,
        (__attribute__((address_space(3))) void*)lptr, 16, 0, 0);
}

// ---------------------------------------------------------------------------
// embb = bf16(emb) : 2048 x 256.  A-operand for the table builders + levels' x.
// ---------------------------------------------------------------------------
__global__ __launch_bounds__(256) void embb_kernel(
    const float* __restrict__ emb, unsigned short* __restrict__ embb)
{
    const int t = blockIdx.x * 256 + threadIdx.x;
    const float4 v0 = *(const float4*)(emb + (size_t)t * 8);
    const float4 v1 = *(const float4*)(emb + (size_t)t * 8 + 4);
    short8v o;
    o[0] = (short)f2bf(v0.x); o[1] = (short)f2bf(v0.y);
    o[2] = (short)f2bf(v0.z); o[3] = (short)f2bf(v0.w);
    o[4] = (short)f2bf(v1.x); o[5] = (short)f2bf(v1.y);
    o[6] = (short)f2bf(v1.z); o[7] = (short)f2bf(v1.w);
    *(short8v*)(embb + (size_t)t * 8) = o;
}

// ---------------------------------------------------------------------------
// WTf: fragment-ready bf16 repack of [Ul;Ur;Wx] (K=768, N=1280) for MFMA B.
// short8 index = (ng*24 + ks)*64 + lane ; lane = q*16 + c
//   holds B[k = ks*32 + q*8 + j][col = ng*16 + c],  j = 0..7
// Fold levels use all 24 ks; table builders use ks_base 0 (Ul), 8 (Ur),
// 16 (Wx) with 8 ks each (K=256).
// ---------------------------------------------------------------------------
__global__ __launch_bounds__(256) void prep_wtf(
    const float* __restrict__ Ul, const float* __restrict__ Ur,
    const float* __restrict__ Wx, unsigned short* __restrict__ WTf)
{
    const int t = blockIdx.x * 256 + threadIdx.x;   // 0..122879
    const int l = t & 63;
    const int q = l >> 4, c = l & 15;
    const int ks = (t >> 6) % 24;
    const int ng = t / (24 * 64);                    // 0..79
    const int col = ng * 16 + c;
    const int k = ks * 32 + q * 8;
    const float* src = (k < 256) ? (Ul + (size_t)k * NG + col)
                     : (k < 512) ? (Ur + (size_t)(k - 256) * NG + col)
                                 : (Wx + (size_t)(k - 512) * NG + col);
    short8v v;
    #pragma unroll
    for (int j = 0; j < 8; ++j) v[j] = (short)f2bf(src[(size_t)j * NG]);
    *(short8v*)(WTf + (size_t)t * 8) = v;
}

// ---------------------------------------------------------------------------
// gemm_tab: O[2048][1280] = bf16( A(2048x256) @ Wsec(256x1280) [+ bias] ).
// Wsec = ks_base0 + 8*blockIdx.z (0=Ul, 8=Ur, 16=Wx); O = z ? O1 : O0 --
// the two HU builds run as ONE launch with gridDim.z=2.  TAB=true also
// computes the leaf h/c tables in-epilogue from acc (absorbs leaftab).
// ---------------------------------------------------------------------------
template <bool TAB>
__global__ __launch_bounds__(256, 2) void gemm_tab(
    const unsigned short* __restrict__ WTf, const unsigned short* __restrict__ A,
    const float* __restrict__ bias, unsigned short* __restrict__ O0,
    unsigned short* __restrict__ O1,
    unsigned short* __restrict__ Hleaf, unsigned short* __restrict__ Cleaf,
    const int ks_base0)
{
    __shared__ __align__(16) unsigned short Ab[2][4096];   // 16 KB A dbuf
    __shared__ __align__(16) unsigned short wbE[20480];    // 40 KB: 5 gates x 64 rows x 64 cols

    const int tid  = threadIdx.x;
    const int lane = tid & 63;
    const int w    = tid >> 6;                  // 0..3 = col-tile
    const int quad = lane >> 4, col15 = lane & 15;
    const int jt = blockIdx.x;
    const int rowBase = blockIdx.y * 64;        // A row
    const int jbase   = jt * 64;
    const int ks_base = ks_base0 + (int)blockIdx.z * 8;
    unsigned short* O = blockIdx.z ? O1 : O0;

    const unsigned short* agp[2];
    unsigned short* ldst[2];
    #pragma unroll
    for (int t = 0; t < 2; ++t) {
        const int ch = 2 * w + t, sub = ch >> 2, rt = ch & 3;
        const int srow = rowBase + rt * 16 + col15;
        agp[t]  = A + (size_t)srow * HDIM + sub * 32 + quad * 8;
        ldst[t] = &Ab[0][0] + ch * 512;
    }

    const short8v* WTfv = (const short8v*)WTf;
    uint32 boff[5];
    #pragma unroll
    for (int g = 0; g < 5; ++g)
        boff[g] = (uint32)(((g * 16 + jt * 4 + w) * 24 + ks_base) * 64 + lane);

    float4v acc[4][5];
    #pragma unroll
    for (int rt = 0; rt < 4; ++rt)
        #pragma unroll
        for (int g = 0; g < 5; ++g)
            #pragma unroll
            for (int e = 0; e < 4; ++e) acc[rt][g][e] = 0.0f;

    dma16(agp[0], ldst[0]); dma16(agp[1], ldst[1]);
    __syncthreads();

    #pragma unroll
    for (int s = 0; s < 4; ++s) {
        if (s < 3) {
            dma16(agp[0] + (s + 1) * 64, ldst[0] + ((s + 1) & 1) * 4096);
            dma16(agp[1] + (s + 1) * 64, ldst[1] + ((s + 1) & 1) * 4096);
        }
        #pragma unroll
        for (int sub = 0; sub < 2; ++sub) {
            short8v bf[5];
            #pragma unroll
            for (int g = 0; g < 5; ++g) bf[g] = WTfv[boff[g] + (s * 2 + sub) * 64];
            #pragma unroll
            for (int rt = 0; rt < 4; ++rt) {
                const short8v af = *(const short8v*)&Ab[s & 1][(sub * 4 + rt) * 512 + lane * 8];
                #pragma unroll
                for (int g = 0; g < 5; ++g)
                    acc[rt][g] = __builtin_amdgcn_mfma_f32_16x16x32_bf16(
                        af, bf[g], acc[rt][g], 0, 0, 0);
            }
        }
        __syncthreads();
    }

    const int jl = w * 16 + col15;
    const int j  = jbase + jl;
    float bz[5];
    #pragma unroll
    for (int g = 0; g < 5; ++g) bz[g] = bias ? bias[g * 256 + j] : 0.0f;
    const int jchunk = jl >> 3, jpos = jl & 7;

    if (TAB) {
        // Leaf h/c tables directly from acc (gi=g0, go=g3, gu=g4).
        #pragma unroll
        for (int rt = 0; rt < 4; ++rt) {
            #pragma unroll
            for (int reg = 0; reg < 4; ++reg) {
                const int rr = rt * 16 + quad * 4 + reg;
                const float gi = acc[rt][0][reg] + bz[0];
                const float go = acc[rt][3][reg] + bz[3];
                const float gu = acc[rt][4][reg] + bz[4];
                const float c = sigm(gi) * tanh_fast(gu);
                const float h = sigm(go) * tanh_fast(c);
                Hleaf[(size_t)(rowBase + rr) * HDIM + j] = f2bf(h);
                Cleaf[(size_t)(rowBase + rr) * HDIM + j] = f2bf(c);
            }
        }
    }

    #pragma unroll
    for (int rt = 0; rt < 4; ++rt) {
        #pragma unroll
        for (int reg = 0; reg < 4; ++reg) {
            const int rr = rt * 16 + quad * 4 + reg;
            const int roff = ((jchunk + 2 * quad) & 7) * 8 + jpos;  // (rr>>2)&3==quad
            #pragma unroll
            for (int g = 0; g < 5; ++g)
                wbE[(g * 64 + rr) * 64 + roff] = f2bf(acc[rt][g][reg] + bz[g]);
        }
    }
    __syncthreads();

    #pragma unroll
    for (int k2 = 0; k2 < 10; ++k2) {
        const int c = tid + k2 * 256;                // 0..2559
        const int g = c >> 9, rr = (c >> 3) & 63, u = c & 7;
        const int ru = (u + 2 * ((rr >> 2) & 3)) & 7;
        const short8v v = *(const short8v*)&wbE[(g * 64 + rr) * 64 + ru * 8];
        *(short8v*)(O + (size_t)(rowBase + rr) * NG + g * 256 + jbase + u * 8) = v;
    }
}

// ---------------------------------------------------------------------------
// leafcell: level d=8 WITHOUT a GEMM.  gates = HUl[tokL] + HUr[tokR] +
// EWb[tokN] (bias inside EWb) -> LSTM cell with cl/cr from Cleaf.
// ---------------------------------------------------------------------------
__global__ __launch_bounds__(256) void leafcell_kernel(
    const int* __restrict__ tokens,
    const unsigned short* __restrict__ HUl, const unsigned short* __restrict__ HUr,
    const unsigned short* __restrict__ EWb, const unsigned short* __restrict__ Cleaf,
    unsigned short* __restrict__ hdst, unsigned short* __restrict__ cdst)
{
    const int t = blockIdx.x * 256 + threadIdx.x;   // 0..1048575
    const int row = t >> 5;                          // 0..32767 = b*256 + i
    const int j   = (t & 31) * 8;                    // h-col octet
    const int b = row >> 8, i = row & 255;
    const int tokN = tokens[b * NNODES + 255 + i];
    const int tokL = tokens[b * NNODES + 511 + 2 * i];
    const int tokR = tokens[b * NNODES + 512 + 2 * i];

    const unsigned short* pl = HUl + (size_t)tokL * NG + j;
    const unsigned short* pr = HUr + (size_t)tokR * NG + j;
    const unsigned short* pn = EWb + (size_t)tokN * NG + j;

    float g5[5][8];
    #pragma unroll
    for (int g = 0; g < 5; ++g) {
        const short8v vl = *(const short8v*)(pl + g * 256);
        const short8v vr = *(const short8v*)(pr + g * 256);
        const short8v vn = *(const short8v*)(pn + g * 256);
        #pragma unroll
        for (int e = 0; e < 8; ++e)
            g5[g][e] = bf2f((unsigned short)vl[e]) + bf2f((unsigned short)vr[e])
                     + bf2f((unsigned short)vn[e]);
    }
    const short8v cl8 = *(const short8v*)(Cleaf + (size_t)tokL * HDIM + j);
    const short8v cr8 = *(const short8v*)(Cleaf + (size_t)tokR * HDIM + j);

    short8v ho, co;
    #pragma unroll
    for (int e = 0; e < 8; ++e) {
        const float ii = sigm(g5[0][e]), fl = sigm(g5[1][e]);
        const float fr = sigm(g5[2][e]), oo = sigm(g5[3][e]);
        const float uu = tanh_fast(g5[4][e]);
        const float c = ii * uu + fl * bf2f((unsigned short)cl8[e])
                                + fr * bf2f((unsigned short)cr8[e]);
        const float h = oo * tanh_fast(c);
        co[e] = (short)f2bf(c);
        ho[e] = (short)f2bf(h);
    }
    *(short8v*)(hdst + (size_t)row * HDIM + j) = ho;
    *(short8v*)(cdst + (size_t)row * HDIM + j) = co;
}

// ---------------------------------------------------------------------------
// Levels d=7..0: K=768 fold [hl|hr|x]@[Ul;Ur;Wx], BK=128 (6 steps), bias
// hoisted.
// R14 split (3-run algebra R8/R9/R13): the 1D block-id swizzle wins ONLY at
// d=7 (1024 blocks > 512 co-resident: 77.5->59.5 us); for d<=6 (all blocks
// co-resident) R9's plain 2D rows-fastest grid measured ~25-30 us faster
// tail (VGPR 96 vs 112 codegen).  So:
//   SWZ=true  (d=7):  1D grid, jt=(L>>3)&3, rowTile=(L>>5)*8+(L&7)
//                     (jt-mates same XCD mod 8 AND within a 32-id window).
//   SWZ=false (d<=6): 2D grid, blockIdx.x=rowTile, blockIdx.y=jt -- R9's
//                     exact geometry (jt-mates NRB apart, co-resident).
// ---------------------------------------------------------------------------
template <bool SWZ>
__global__ __launch_bounds__(256, 2) void level_fold(
    const unsigned short* __restrict__ WTf, const int* __restrict__ tokens,
    const unsigned short* __restrict__ embb,
    const unsigned short* __restrict__ hsrc, const unsigned short* __restrict__ csrc,
    const float* __restrict__ bias,
    unsigned short* __restrict__ hdst, unsigned short* __restrict__ cdst,
    float* __restrict__ out, const int d)
{
    const int n = 1 << d;

    __shared__ __align__(16) unsigned short Ab[2][8192];   // 32 KB: dbuf 64r x 128k

    const int tid  = threadIdx.x;
    const int lane = tid & 63;
    const int w    = tid >> 6;
    const int quad = lane >> 4, col15 = lane & 15;

    int jt, rowTile;
    if (SWZ) {
        const int L = blockIdx.x;
        jt      = (L >> 3) & 3;
        rowTile = (L >> 5) * 8 + (L & 7);
    } else {
        jt      = blockIdx.y;
        rowTile = blockIdx.x;
    }
    const int rowBase = rowTile * 64;
    const int jbase   = jt * 64;

    const uint32 inrow = (uint32)(w * 64 + quad * 16);
    uint32 oL[4], oR[4], oN[4];
    #pragma unroll
    for (int t = 0; t < 4; ++t) {
        const int srow = rowBase + t * 16 + col15;
        const int b = srow >> d, i = srow & (n - 1);
        oN[t] = (uint32)tokens[b * NNODES + (n - 1) + i] * 512u + inrow;
        oL[t] = (uint32)(2 * srow) * 512u + inrow;
        oR[t] = oL[t] + 512u;
    }
    const char* hb = (const char*)hsrc;
    const char* xb = (const char*)embb;

    const short8v* WTfv = (const short8v*)WTf;
    uint32 boff[5];
    #pragma unroll
    for (int g = 0; g < 5; ++g)
        boff[g] = ((g * 16 + jt * 4 + w) * 24) * 64 + lane;   // full K=768

    const int jl = w * 16 + col15;
    const int j  = jbase + jl;
    float bz[5];
    #pragma unroll
    for (int g = 0; g < 5; ++g) bz[g] = bias[g * 256 + j];

    float4v acc[4][5];
    #pragma unroll
    for (int rt = 0; rt < 4; ++rt)
        #pragma unroll
        for (int g = 0; g < 5; ++g)
            #pragma unroll
            for (int e = 0; e < 4; ++e) acc[rt][g][e] = 0.0f;

    {
        unsigned short* dst = &Ab[0][0] + w * 2048;
        #pragma unroll
        for (int t = 0; t < 4; ++t)
            dma16((const unsigned short*)(hb + oL[t]), dst + t * 512);
    }
    __syncthreads();

    #pragma unroll
    for (int s = 0; s < 6; ++s) {
        if (s < 5) {
            const int sn = s + 1;
            unsigned short* dst = &Ab[sn & 1][0] + w * 2048;
            #pragma unroll
            for (int t = 0; t < 4; ++t) {
                const char* p = (sn < 2) ? (hb + oL[t] + sn * 256)
                              : (sn < 4) ? (hb + oR[t] + (sn - 2) * 256)
                                         : (xb + oN[t] + (sn - 4) * 256);
                dma16((const unsigned short*)p, dst + t * 512);
            }
        }
        #pragma unroll
        for (int sub = 0; sub < 4; ++sub) {
            short8v bf[5];
            #pragma unroll
            for (int g = 0; g < 5; ++g) bf[g] = WTfv[boff[g] + (s * 4 + sub) * 64];
            #pragma unroll
            for (int rt = 0; rt < 4; ++rt) {
                const short8v af = *(const short8v*)&Ab[s & 1][(sub * 4 + rt) * 512 + lane * 8];
                #pragma unroll
                for (int g = 0; g < 5; ++g)
                    acc[rt][g] = __builtin_amdgcn_mfma_f32_16x16x32_bf16(
                        af, bf[g], acc[rt][g], 0, 0, 0);
            }
        }
        __syncthreads();
    }

    float hv[4][4], cv[4][4];
    #pragma unroll
    for (int rt = 0; rt < 4; ++rt) {
        #pragma unroll
        for (int reg = 0; reg < 4; ++reg) {
            const int rr = rt * 16 + quad * 4 + reg;
            const int grow = rowBase + rr;
            const float cl = bf2f(csrc[(size_t)(2 * grow) * HDIM + j]);
            const float cr = bf2f(csrc[(size_t)(2 * grow + 1) * HDIM + j]);
            const float gi  = acc[rt][0][reg] + bz[0];
            const float gfl = acc[rt][1][reg] + bz[1];
            const float gfr = acc[rt][2][reg] + bz[2];
            const float go  = acc[rt][3][reg] + bz[3];
            const float gu  = acc[rt][4][reg] + bz[4];
            const float ii = sigm(gi), fl = sigm(gfl), fr = sigm(gfr), oo = sigm(go);
            const float uu = tanh_fast(gu);
            const float c = ii * uu + fl * cl + fr * cr;
            const float h = oo * tanh_fast(c);
            cv[rt][reg] = c; hv[rt][reg] = h;
            if (d == 0) out[(size_t)grow * HDIM + j] = h;  // n==1 -> b=row
        }
    }
    if (d == 0) return;   // root level: nothing reads hdst/cdst

    unsigned short* wb = &Ab[0][0];
    const int jchunk = jl >> 3, jpos = jl & 7;
    #pragma unroll
    for (int rt = 0; rt < 4; ++rt) {
        #pragma unroll
        for (int reg = 0; reg < 4; ++reg) {
            const int rr = rt * 16 + quad * 4 + reg;
            const int roff = ((jchunk + 2 * quad) & 7) * 8 + jpos;
            wb[rr * 64 + roff]        = f2bf(hv[rt][reg]);
            wb[4096 + rr * 64 + roff] = f2bf(cv[rt][reg]);
        }
    }
    __syncthreads();
    #pragma unroll
    for (int k2 = 0; k2 < 4; ++k2) {
        const int c = tid + k2 * 256;
        const int arr = c >> 9, rr = (c >> 3) & 63, u = c & 7;
        const int ru = (u + 2 * ((rr >> 2) & 3)) & 7;
        const short8v v = *(const short8v*)(wb + (arr * 4096 + rr * 64 + ru * 8));
        unsigned short* dstp = (arr ? cdst : hdst) +
            (size_t)(rowBase + rr) * HDIM + jbase + u * 8;
        *(short8v*)dstp = v;
    }
}

// ---------------------------------------------------------------------------
extern "C" void kernel_launch(void* const* d_in, const int* in_sizes, int n_in,
                              void* d_out, int out_size, void* d_ws, size_t ws_size,
                              hipStream_t stream)
{
    const int*   tokens = (const int*)d_in[0];
    const float* emb    = (const float*)d_in[1];
    const float* Wx     = (const float*)d_in[2];
    const float* Ul     = (const float*)d_in[3];
    const float* Ur     = (const float*)d_in[4];
    const float* bias   = (const float*)d_in[5];
    float* out = (float*)d_out;

    // Workspace (bf16): EWb 5.24 | HUl 5.24 | HUr 5.24 | embb 1.05 | WTf 1.97
    // | Hleaf+Cleaf 2.1 | hA,cA 2x8.4 | hB,cB 2x16.8  -> ~70 MB total.
    const size_t EW_ELEMS  = (size_t)VOCAB * NG;          // also HUl/HUr size
    const size_t EMB_ELEMS = (size_t)VOCAB * HDIM;
    const size_t WTF_ELEMS = (size_t)80 * 24 * 64 * 8;
    const size_t LT_ELEMS  = (size_t)VOCAB * HDIM;        // each of Hleaf, Cleaf
    const size_t SLOT_A    = (size_t)16384 * HDIM;        // d=7,5,3,1 outputs
    const size_t SLOT_B    = (size_t)32768 * HDIM;        // d=8,6,4,2,0 outputs
    const size_t REQUIRED  = (3 * EW_ELEMS + EMB_ELEMS + WTF_ELEMS + 2 * LT_ELEMS
                              + 2 * (SLOT_A + SLOT_B)) * 2;
    if (ws_size < REQUIRED || d_ws == nullptr) return;   // clean fail, not a fault

    char* ws = (char*)d_ws;
    unsigned short* EWb   = (unsigned short*)ws;
    unsigned short* HUl   = EWb + EW_ELEMS;
    unsigned short* HUr   = HUl + EW_ELEMS;
    unsigned short* embb  = HUr + EW_ELEMS;
    unsigned short* WTf   = embb + EMB_ELEMS;
    unsigned short* Hleaf = WTf + WTF_ELEMS;
    unsigned short* Cleaf = Hleaf + LT_ELEMS;
    unsigned short* hA    = Cleaf + LT_ELEMS;
    unsigned short* cA    = hA + SLOT_A;
    unsigned short* hB    = cA + SLOT_A;
    unsigned short* cB    = hB + SLOT_B;

    embb_kernel<<<dim3(256), 256, 0, stream>>>(emb, embb);
    prep_wtf<<<dim3(480), 256, 0, stream>>>(Ul, Ur, Wx, WTf);
    // EWb = x@Wx + b, with leaf h/c tables fused into the epilogue.
    gemm_tab<true><<<dim3(4, 32, 1), 256, 0, stream>>>(
        WTf, embb, bias, EWb, nullptr, Hleaf, Cleaf, 16);
    // HUl = Hleaf@Ul and HUr = Hleaf@Ur in ONE launch (z selects section).
    gemm_tab<false><<<dim3(4, 32, 2), 256, 0, stream>>>(
        WTf, Hleaf, nullptr, HUl, HUr, nullptr, nullptr, 0);

    // Level d=8: pure table gather + cell (no GEMM).  Writes B-slot.
    leafcell_kernel<<<dim3(4096), 256, 0, stream>>>(
        tokens, HUl, HUr, EWb, Cleaf, hB, cB);

    // d=7: swizzle variant (1D grid; beats 2D by 18 us at 1024 blocks).
    level_fold<true><<<dim3(4 * 256), 256, 0, stream>>>(
        WTf, tokens, embb, hB, cB, bias, hA, cA, out, 7);

    // d=6..0: R9's 2D rows-fastest variant (best measured tail).
    for (int d = 6; d >= 0; --d) {
        const int NRB = 2 << d;
        const bool evenD = ((d & 1) == 0);
        const unsigned short* hs = evenD ? hA : hB;
        const unsigned short* cs = evenD ? cA : cB;
        unsigned short* hd = evenD ? hB : hA;
        unsigned short* cd = evenD ? cB : cA;
        level_fold<false><<<dim3(NRB, 4), 256, 0, stream>>>(
            WTf, tokens, embb, hs, cs, bias, hd, cd, out, d);
    }
}

// Round 15
// 326.424 us; speedup vs baseline: 1.0345x; 1.0042x over previous
//
#include <hip/hip_runtime.h>
#include <hip/hip_bf16.h>
#include <math.h>

// Problem constants (from reference)
#define B_SZ   128
#define HDIM   256
#define NG     1280     // 5*H
#define NNODES 1023
#define VOCAB  2048

typedef unsigned int uint32;
typedef short  short8v  __attribute__((ext_vector_type(8)));   // 8 x bf16 (4 VGPR)
typedef float  float4v  __attribute__((ext_vector_type(4)));   // MFMA C/D frag

__device__ __forceinline__ float sigm(float x) {
    return 1.0f / (1.0f + __expf(-x));
}
__device__ __forceinline__ float tanh_fast(float x) {
    return 2.0f / (1.0f + __expf(-2.0f * x)) - 1.0f;
}
__device__ __forceinline__ float bf2f(unsigned short u) {
    return __uint_as_float(((uint32)u) << 16);
}
__device__ __forceinline__ unsigned short f2bf(float f) {
    uint32 x = __float_as_uint(f);
    uint32 r = (x + 0x7FFFu + ((x >> 16) & 1u)) >> 16;   // RNE
    return (unsigned short)r;
}

// Async 16B/lane global->LDS DMA. LDS dest = wave-uniform base + lane*16.
__device__ __forceinline__ void dma16(const unsigned short* gptr, unsigned short* lptr) {
    __builtin_amdgcn_global_load_lds(
        (const __attribute__((address_space(1))) void*)gptr,
        (__attribute__((address_space(3))) void*)lptr, 16, 0, 0);
}

// ---------------------------------------------------------------------------
// embb = bf16(emb) : 2048 x 256.  A-operand for the table builders + levels' x.
// ---------------------------------------------------------------------------
__global__ __launch_bounds__(256) void embb_kernel(
    const float* __restrict__ emb, unsigned short* __restrict__ embb)
{
    const int t = blockIdx.x * 256 + threadIdx.x;
    const float4 v0 = *(const float4*)(emb + (size_t)t * 8);
    const float4 v1 = *(const float4*)(emb + (size_t)t * 8 + 4);
    short8v o;
    o[0] = (short)f2bf(v0.x); o[1] = (short)f2bf(v0.y);
    o[2] = (short)f2bf(v0.z); o[3] = (short)f2bf(v0.w);
    o[4] = (short)f2bf(v1.x); o[5] = (short)f2bf(v1.y);
    o[6] = (short)f2bf(v1.z); o[7] = (short)f2bf(v1.w);
    *(short8v*)(embb + (size_t)t * 8) = o;
}

// ---------------------------------------------------------------------------
// WTf: fragment-ready bf16 repack of [Ul;Ur;Wx] (K=768, N=1280) for MFMA B.
// short8 index = (ng*24 + ks)*64 + lane ; lane = q*16 + c
//   holds B[k = ks*32 + q*8 + j][col = ng*16 + c],  j = 0..7
// ---------------------------------------------------------------------------
__global__ __launch_bounds__(256) void prep_wtf(
    const float* __restrict__ Ul, const float* __restrict__ Ur,
    const float* __restrict__ Wx, unsigned short* __restrict__ WTf)
{
    const int t = blockIdx.x * 256 + threadIdx.x;   // 0..122879
    const int l = t & 63;
    const int q = l >> 4, c = l & 15;
    const int ks = (t >> 6) % 24;
    const int ng = t / (24 * 64);                    // 0..79
    const int col = ng * 16 + c;
    const int k = ks * 32 + q * 8;
    const float* src = (k < 256) ? (Ul + (size_t)k * NG + col)
                     : (k < 512) ? (Ur + (size_t)(k - 256) * NG + col)
                                 : (Wx + (size_t)(k - 512) * NG + col);
    short8v v;
    #pragma unroll
    for (int j = 0; j < 8; ++j) v[j] = (short)f2bf(src[(size_t)j * NG]);
    *(short8v*)(WTf + (size_t)t * 8) = v;
}

// ---------------------------------------------------------------------------
// gemm_tab: O[2048][1280] = bf16( A(2048x256) @ Wsec(256x1280) [+ bias] ).
// Wsec = ks_base0 + 8*blockIdx.z (0=Ul, 8=Ur, 16=Wx); O = z ? O1 : O0.
// TAB=true also computes the leaf h/c tables in-epilogue from acc.
// R15: RT = row-tiles of 16 per block.  RT=2 (32-row tiles) doubles the
// grid (TAB 128->256 blocks, HU 256->512) -- these dispatches were
// latency-bound at half fill; more blocks = more latency hiding.
// ---------------------------------------------------------------------------
template <bool TAB, int RT>
__global__ __launch_bounds__(256, 2) void gemm_tab(
    const unsigned short* __restrict__ WTf, const unsigned short* __restrict__ A,
    const float* __restrict__ bias, unsigned short* __restrict__ O0,
    unsigned short* __restrict__ O1,
    unsigned short* __restrict__ Hleaf, unsigned short* __restrict__ Cleaf,
    const int ks_base0)
{
    constexpr int M   = RT * 16;        // rows per block
    constexpr int CPW = RT / 2 ? RT / 2 : 1;   // staging chunks per wave (RT=2 -> 1, RT=4 -> 2)
    __shared__ __align__(16) unsigned short Ab[2][RT * 1024];   // dbuf: M rows x 64 k
    __shared__ __align__(16) unsigned short wbE[RT * 5120];     // 5 gates x M rows x 64 cols

    const int tid  = threadIdx.x;
    const int lane = tid & 63;
    const int w    = tid >> 6;                  // 0..3 = col-tile
    const int quad = lane >> 4, col15 = lane & 15;
    const int jt = blockIdx.x;
    const int rowBase = blockIdx.y * M;         // A row
    const int jbase   = jt * 64;
    const int ks_base = ks_base0 + (int)blockIdx.z * 8;
    unsigned short* O = blockIdx.z ? O1 : O0;

    const unsigned short* agp[CPW];
    unsigned short* ldst[CPW];
    #pragma unroll
    for (int t = 0; t < CPW; ++t) {
        const int ch = CPW * w + t, sub = ch / RT, rt = ch % RT;
        const int srow = rowBase + rt * 16 + col15;
        agp[t]  = A + (size_t)srow * HDIM + sub * 32 + quad * 8;
        ldst[t] = &Ab[0][0] + ch * 512;
    }

    const short8v* WTfv = (const short8v*)WTf;
    uint32 boff[5];
    #pragma unroll
    for (int g = 0; g < 5; ++g)
        boff[g] = (uint32)(((g * 16 + jt * 4 + w) * 24 + ks_base) * 64 + lane);

    float4v acc[RT][5];
    #pragma unroll
    for (int rt = 0; rt < RT; ++rt)
        #pragma unroll
        for (int g = 0; g < 5; ++g)
            #pragma unroll
            for (int e = 0; e < 4; ++e) acc[rt][g][e] = 0.0f;

    #pragma unroll
    for (int t = 0; t < CPW; ++t) dma16(agp[t], ldst[t]);
    __syncthreads();

    #pragma unroll
    for (int s = 0; s < 4; ++s) {
        if (s < 3) {
            #pragma unroll
            for (int t = 0; t < CPW; ++t)
                dma16(agp[t] + (s + 1) * 64, ldst[t] + ((s + 1) & 1) * (RT * 1024));
        }
        #pragma unroll
        for (int sub = 0; sub < 2; ++sub) {
            short8v bf[5];
            #pragma unroll
            for (int g = 0; g < 5; ++g) bf[g] = WTfv[boff[g] + (s * 2 + sub) * 64];
            #pragma unroll
            for (int rt = 0; rt < RT; ++rt) {
                const short8v af = *(const short8v*)&Ab[s & 1][(sub * RT + rt) * 512 + lane * 8];
                #pragma unroll
                for (int g = 0; g < 5; ++g)
                    acc[rt][g] = __builtin_amdgcn_mfma_f32_16x16x32_bf16(
                        af, bf[g], acc[rt][g], 0, 0, 0);
            }
        }
        __syncthreads();
    }

    const int jl = w * 16 + col15;
    const int j  = jbase + jl;
    float bz[5];
    #pragma unroll
    for (int g = 0; g < 5; ++g) bz[g] = bias ? bias[g * 256 + j] : 0.0f;
    const int jchunk = jl >> 3, jpos = jl & 7;

    if (TAB) {
        // Leaf h/c tables directly from acc (gi=g0, go=g3, gu=g4).
        #pragma unroll
        for (int rt = 0; rt < RT; ++rt) {
            #pragma unroll
            for (int reg = 0; reg < 4; ++reg) {
                const int rr = rt * 16 + quad * 4 + reg;
                const float gi = acc[rt][0][reg] + bz[0];
                const float go = acc[rt][3][reg] + bz[3];
                const float gu = acc[rt][4][reg] + bz[4];
                const float c = sigm(gi) * tanh_fast(gu);
                const float h = sigm(go) * tanh_fast(c);
                Hleaf[(size_t)(rowBase + rr) * HDIM + j] = f2bf(h);
                Cleaf[(size_t)(rowBase + rr) * HDIM + j] = f2bf(c);
            }
        }
    }

    #pragma unroll
    for (int rt = 0; rt < RT; ++rt) {
        #pragma unroll
        for (int reg = 0; reg < 4; ++reg) {
            const int rr = rt * 16 + quad * 4 + reg;
            const int roff = ((jchunk + 2 * quad) & 7) * 8 + jpos;  // (rr>>2)&3==quad
            #pragma unroll
            for (int g = 0; g < 5; ++g)
                wbE[(g * M + rr) * 64 + roff] = f2bf(acc[rt][g][reg] + bz[g]);
        }
    }
    __syncthreads();

    #pragma unroll
    for (int k2 = 0; k2 < RT * 5 / 2; ++k2) {       // 5*M*8/256 iterations
        const int c = tid + k2 * 256;                // short8 index
        const int g = c / (M * 8), rr = (c >> 3) & (M - 1), u = c & 7;
        const int ru = (u + 2 * ((rr >> 2) & 3)) & 7;
        const short8v v = *(const short8v*)&wbE[(g * M + rr) * 64 + ru * 8];
        *(short8v*)(O + (size_t)(rowBase + rr) * NG + g * 256 + jbase + u * 8) = v;
    }
}

// ---------------------------------------------------------------------------
// leafcell: level d=8 WITHOUT a GEMM.  gates = HUl[tokL] + HUr[tokR] +
// EWb[tokN] (bias inside EWb) -> LSTM cell with cl/cr from Cleaf.
// R15: 2 col-octets per thread (j, j+128): half the threads (2048 blocks),
// 2x loads in flight per thread -> better gather-latency hiding.
// ---------------------------------------------------------------------------
__global__ __launch_bounds__(256) void leafcell_kernel(
    const int* __restrict__ tokens,
    const unsigned short* __restrict__ HUl, const unsigned short* __restrict__ HUr,
    const unsigned short* __restrict__ EWb, const unsigned short* __restrict__ Cleaf,
    unsigned short* __restrict__ hdst, unsigned short* __restrict__ cdst)
{
    const int t = blockIdx.x * 256 + threadIdx.x;   // 0..524287
    const int row = t >> 4;                          // 0..32767 = b*256 + i
    const int j0  = (t & 15) * 8;                    // first octet; second = j0+128
    const int b = row >> 8, i = row & 255;
    const int tokN = tokens[b * NNODES + 255 + i];
    const int tokL = tokens[b * NNODES + 511 + 2 * i];
    const int tokR = tokens[b * NNODES + 512 + 2 * i];

    const unsigned short* pl = HUl + (size_t)tokL * NG + j0;
    const unsigned short* pr = HUr + (size_t)tokR * NG + j0;
    const unsigned short* pn = EWb + (size_t)tokN * NG + j0;

    float g5[5][2][8];
    #pragma unroll
    for (int g = 0; g < 5; ++g) {
        #pragma unroll
        for (int h2 = 0; h2 < 2; ++h2) {
            const short8v vl = *(const short8v*)(pl + g * 256 + h2 * 128);
            const short8v vr = *(const short8v*)(pr + g * 256 + h2 * 128);
            const short8v vn = *(const short8v*)(pn + g * 256 + h2 * 128);
            #pragma unroll
            for (int e = 0; e < 8; ++e)
                g5[g][h2][e] = bf2f((unsigned short)vl[e]) + bf2f((unsigned short)vr[e])
                             + bf2f((unsigned short)vn[e]);
        }
    }
    #pragma unroll
    for (int h2 = 0; h2 < 2; ++h2) {
        const short8v cl8 = *(const short8v*)(Cleaf + (size_t)tokL * HDIM + j0 + h2 * 128);
        const short8v cr8 = *(const short8v*)(Cleaf + (size_t)tokR * HDIM + j0 + h2 * 128);
        short8v ho, co;
        #pragma unroll
        for (int e = 0; e < 8; ++e) {
            const float ii = sigm(g5[0][h2][e]), fl = sigm(g5[1][h2][e]);
            const float fr = sigm(g5[2][h2][e]), oo = sigm(g5[3][h2][e]);
            const float uu = tanh_fast(g5[4][h2][e]);
            const float c = ii * uu + fl * bf2f((unsigned short)cl8[e])
                                    + fr * bf2f((unsigned short)cr8[e]);
            const float h = oo * tanh_fast(c);
            co[e] = (short)f2bf(c);
            ho[e] = (short)f2bf(h);
        }
        *(short8v*)(hdst + (size_t)row * HDIM + j0 + h2 * 128) = ho;
        *(short8v*)(cdst + (size_t)row * HDIM + j0 + h2 * 128) = co;
    }
}

// ---------------------------------------------------------------------------
// Levels d=7..0: K=768 fold [hl|hr|x]@[Ul;Ur;Wx], BK=128 (6 steps), bias
// hoisted.  SWZ=true (d=7 only): 1D grid, jt=(L>>3)&3, rowTile=(L>>5)*8+(L&7)
// -- jt-mates co-XCD AND co-resident (d7 77.5->59.5 us, 3x confirmed).
// SWZ=false (d<=6): 2D grid (rowTile, jt) -- all blocks co-resident.
// [R14 note: the R9-tail "advantage" was a single-run outlier; four runs
// cluster at 268-278 us non-d7, so mapping choice for d<=6 is noise-level.]
// ---------------------------------------------------------------------------
template <bool SWZ>
__global__ __launch_bounds__(256, 2) void level_fold(
    const unsigned short* __restrict__ WTf, const int* __restrict__ tokens,
    const unsigned short* __restrict__ embb,
    const unsigned short* __restrict__ hsrc, const unsigned short* __restrict__ csrc,
    const float* __restrict__ bias,
    unsigned short* __restrict__ hdst, unsigned short* __restrict__ cdst,
    float* __restrict__ out, const int d)
{
    const int n = 1 << d;

    __shared__ __align__(16) unsigned short Ab[2][8192];   // 32 KB: dbuf 64r x 128k

    const int tid  = threadIdx.x;
    const int lane = tid & 63;
    const int w    = tid >> 6;
    const int quad = lane >> 4, col15 = lane & 15;

    int jt, rowTile;
    if (SWZ) {
        const int L = blockIdx.x;
        jt      = (L >> 3) & 3;
        rowTile = (L >> 5) * 8 + (L & 7);
    } else {
        jt      = blockIdx.y;
        rowTile = blockIdx.x;
    }
    const int rowBase = rowTile * 64;
    const int jbase   = jt * 64;

    const uint32 inrow = (uint32)(w * 64 + quad * 16);
    uint32 oL[4], oR[4], oN[4];
    #pragma unroll
    for (int t = 0; t < 4; ++t) {
        const int srow = rowBase + t * 16 + col15;
        const int b = srow >> d, i = srow & (n - 1);
        oN[t] = (uint32)tokens[b * NNODES + (n - 1) + i] * 512u + inrow;
        oL[t] = (uint32)(2 * srow) * 512u + inrow;
        oR[t] = oL[t] + 512u;
    }
    const char* hb = (const char*)hsrc;
    const char* xb = (const char*)embb;

    const short8v* WTfv = (const short8v*)WTf;
    uint32 boff[5];
    #pragma unroll
    for (int g = 0; g < 5; ++g)
        boff[g] = ((g * 16 + jt * 4 + w) * 24) * 64 + lane;   // full K=768

    const int jl = w * 16 + col15;
    const int j  = jbase + jl;
    float bz[5];
    #pragma unroll
    for (int g = 0; g < 5; ++g) bz[g] = bias[g * 256 + j];

    float4v acc[4][5];
    #pragma unroll
    for (int rt = 0; rt < 4; ++rt)
        #pragma unroll
        for (int g = 0; g < 5; ++g)
            #pragma unroll
            for (int e = 0; e < 4; ++e) acc[rt][g][e] = 0.0f;

    {
        unsigned short* dst = &Ab[0][0] + w * 2048;
        #pragma unroll
        for (int t = 0; t < 4; ++t)
            dma16((const unsigned short*)(hb + oL[t]), dst + t * 512);
    }
    __syncthreads();

    #pragma unroll
    for (int s = 0; s < 6; ++s) {
        if (s < 5) {
            const int sn = s + 1;
            unsigned short* dst = &Ab[sn & 1][0] + w * 2048;
            #pragma unroll
            for (int t = 0; t < 4; ++t) {
                const char* p = (sn < 2) ? (hb + oL[t] + sn * 256)
                              : (sn < 4) ? (hb + oR[t] + (sn - 2) * 256)
                                         : (xb + oN[t] + (sn - 4) * 256);
                dma16((const unsigned short*)p, dst + t * 512);
            }
        }
        #pragma unroll
        for (int sub = 0; sub < 4; ++sub) {
            short8v bf[5];
            #pragma unroll
            for (int g = 0; g < 5; ++g) bf[g] = WTfv[boff[g] + (s * 4 + sub) * 64];
            #pragma unroll
            for (int rt = 0; rt < 4; ++rt) {
                const short8v af = *(const short8v*)&Ab[s & 1][(sub * 4 + rt) * 512 + lane * 8];
                #pragma unroll
                for (int g = 0; g < 5; ++g)
                    acc[rt][g] = __builtin_amdgcn_mfma_f32_16x16x32_bf16(
                        af, bf[g], acc[rt][g], 0, 0, 0);
            }
        }
        __syncthreads();
    }

    float hv[4][4], cv[4][4];
    #pragma unroll
    for (int rt = 0; rt < 4; ++rt) {
        #pragma unroll
        for (int reg = 0; reg < 4; ++reg) {
            const int rr = rt * 16 + quad * 4 + reg;
            const int grow = rowBase + rr;
            const float cl = bf2f(csrc[(size_t)(2 * grow) * HDIM + j]);
            const float cr = bf2f(csrc[(size_t)(2 * grow + 1) * HDIM + j]);
            const float gi  = acc[rt][0][reg] + bz[0];
            const float gfl = acc[rt][1][reg] + bz[1];
            const float gfr = acc[rt][2][reg] + bz[2];
            const float go  = acc[rt][3][reg] + bz[3];
            const float gu  = acc[rt][4][reg] + bz[4];
            const float ii = sigm(gi), fl = sigm(gfl), fr = sigm(gfr), oo = sigm(go);
            const float uu = tanh_fast(gu);
            const float c = ii * uu + fl * cl + fr * cr;
            const float h = oo * tanh_fast(c);
            cv[rt][reg] = c; hv[rt][reg] = h;
            if (d == 0) out[(size_t)grow * HDIM + j] = h;  // n==1 -> b=row
        }
    }
    if (d == 0) return;   // root level: nothing reads hdst/cdst

    unsigned short* wb = &Ab[0][0];
    const int jchunk = jl >> 3, jpos = jl & 7;
    #pragma unroll
    for (int rt = 0; rt < 4; ++rt) {
        #pragma unroll
        for (int reg = 0; reg < 4; ++reg) {
            const int rr = rt * 16 + quad * 4 + reg;
            const int roff = ((jchunk + 2 * quad) & 7) * 8 + jpos;
            wb[rr * 64 + roff]        = f2bf(hv[rt][reg]);
            wb[4096 + rr * 64 + roff] = f2bf(cv[rt][reg]);
        }
    }
    __syncthreads();
    #pragma unroll
    for (int k2 = 0; k2 < 4; ++k2) {
        const int c = tid + k2 * 256;
        const int arr = c >> 9, rr = (c >> 3) & 63, u = c & 7;
        const int ru = (u + 2 * ((rr >> 2) & 3)) & 7;
        const short8v v = *(const short8v*)(wb + (arr * 4096 + rr * 64 + ru * 8));
        unsigned short* dstp = (arr ? cdst : hdst) +
            (size_t)(rowBase + rr) * HDIM + jbase + u * 8;
        *(short8v*)dstp = v;
    }
}

// ---------------------------------------------------------------------------
extern "C" void kernel_launch(void* const* d_in, const int* in_sizes, int n_in,
                              void* d_out, int out_size, void* d_ws, size_t ws_size,
                              hipStream_t stream)
{
    const int*   tokens = (const int*)d_in[0];
    const float* emb    = (const float*)d_in[1];
    const float* Wx     = (const float*)d_in[2];
    const float* Ul     = (const float*)d_in[3];
    const float* Ur     = (const float*)d_in[4];
    const float* bias   = (const float*)d_in[5];
    float* out = (float*)d_out;

    // Workspace (bf16): EWb 5.24 | HUl 5.24 | HUr 5.24 | embb 1.05 | WTf 1.97
    // | Hleaf+Cleaf 2.1 | hA,cA 2x8.4 | hB,cB 2x16.8  -> ~70 MB total.
    const size_t EW_ELEMS  = (size_t)VOCAB * NG;          // also HUl/HUr size
    const size_t EMB_ELEMS = (size_t)VOCAB * HDIM;
    const size_t WTF_ELEMS = (size_t)80 * 24 * 64 * 8;
    const size_t LT_ELEMS  = (size_t)VOCAB * HDIM;        // each of Hleaf, Cleaf
    const size_t SLOT_A    = (size_t)16384 * HDIM;        // d=7,5,3,1 outputs
    const size_t SLOT_B    = (size_t)32768 * HDIM;        // d=8,6,4,2,0 outputs
    const size_t REQUIRED  = (3 * EW_ELEMS + EMB_ELEMS + WTF_ELEMS + 2 * LT_ELEMS
                              + 2 * (SLOT_A + SLOT_B)) * 2;
    if (ws_size < REQUIRED || d_ws == nullptr) return;   // clean fail, not a fault

    char* ws = (char*)d_ws;
    unsigned short* EWb   = (unsigned short*)ws;
    unsigned short* HUl   = EWb + EW_ELEMS;
    unsigned short* HUr   = HUl + EW_ELEMS;
    unsigned short* embb  = HUr + EW_ELEMS;
    unsigned short* WTf   = embb + EMB_ELEMS;
    unsigned short* Hleaf = WTf + WTF_ELEMS;
    unsigned short* Cleaf = Hleaf + LT_ELEMS;
    unsigned short* hA    = Cleaf + LT_ELEMS;
    unsigned short* cA    = hA + SLOT_A;
    unsigned short* hB    = cA + SLOT_A;
    unsigned short* cB    = hB + SLOT_B;

    embb_kernel<<<dim3(256), 256, 0, stream>>>(emb, embb);
    prep_wtf<<<dim3(480), 256, 0, stream>>>(Ul, Ur, Wx, WTf);
    // EWb = x@Wx + b, leaf h/c tables fused; 32-row tiles -> 256 blocks.
    gemm_tab<true, 2><<<dim3(4, 64, 1), 256, 0, stream>>>(
        WTf, embb, bias, EWb, nullptr, Hleaf, Cleaf, 16);
    // HUl = Hleaf@Ul and HUr = Hleaf@Ur in ONE launch; 512 blocks.
    gemm_tab<false, 2><<<dim3(4, 64, 2), 256, 0, stream>>>(
        WTf, Hleaf, nullptr, HUl, HUr, nullptr, nullptr, 0);

    // Level d=8: pure table gather + cell (no GEMM).  Writes B-slot.
    leafcell_kernel<<<dim3(2048), 256, 0, stream>>>(
        tokens, HUl, HUr, EWb, Cleaf, hB, cB);

    // d=7: swizzle variant (1D grid; 59 us, 3x confirmed).
    level_fold<true><<<dim3(4 * 256), 256, 0, stream>>>(
        WTf, tokens, embb, hB, cB, bias, hA, cA, out, 7);

    // d=6..0: 2D rows-fastest variant.
    for (int d = 6; d >= 0; --d) {
        const int NRB = 2 << d;
        const bool evenD = ((d & 1) == 0);
        const unsigned short* hs = evenD ? hA : hB;
        const unsigned short* cs = evenD ? cA : cB;
        unsigned short* hd = evenD ? hB : hA;
        unsigned short* cd = evenD ? cB : cA;
        level_fold<false><<<dim3(NRB, 4), 256, 0, stream>>>(
            WTf, tokens, embb, hs, cs, bias, hd, cd, out, d);
    }
}

// Round 16
// 318.573 us; speedup vs baseline: 1.0600x; 1.0246x over previous
//
#include <hip/hip_runtime.h>
#include <hip/hip_bf16.h>
#include <math.h>

// Problem constants (from reference)
#define B_SZ   128
#define HDIM   256
#define NG     1280     // 5*H
#define NNODES 1023
#define VOCAB  2048

typedef unsigned int uint32;
typedef short  short8v  __attribute__((ext_vector_type(8)));   // 8 x bf16 (4 VGPR)
typedef float  float4v  __attribute__((ext_vector_type(4)));   // MFMA C/D frag

__device__ __forceinline__ float sigm(float x) {
    return 1.0f / (1.0f + __expf(-x));
}
__device__ __forceinline__ float tanh_fast(float x) {
    return 2.0f / (1.0f + __expf(-2.0f * x)) - 1.0f;
}
__device__ __forceinline__ float bf2f(unsigned short u) {
    return __uint_as_float(((uint32)u) << 16);
}
__device__ __forceinline__ unsigned short f2bf(float f) {
    uint32 x = __float_as_uint(f);
    uint32 r = (x + 0x7FFFu + ((x >> 16) & 1u)) >> 16;   // RNE
    return (unsigned short)r;
}

// Async 16B/lane global->LDS DMA. LDS dest = wave-uniform base + lane*16.
__device__ __forceinline__ void dma16(const unsigned short* gptr, unsigned short* lptr) {
    __builtin_amdgcn_global_load_lds(
        (const __attribute__((address_space(1))) void*)gptr,
        (__attribute__((address_space(3))) void*)lptr, 16, 0, 0);
}

// ---------------------------------------------------------------------------
// embb = bf16(emb) : 2048 x 256.  A-operand for the table builders + levels' x.
// ---------------------------------------------------------------------------
__global__ __launch_bounds__(256) void embb_kernel(
    const float* __restrict__ emb, unsigned short* __restrict__ embb)
{
    const int t = blockIdx.x * 256 + threadIdx.x;
    const float4 v0 = *(const float4*)(emb + (size_t)t * 8);
    const float4 v1 = *(const float4*)(emb + (size_t)t * 8 + 4);
    short8v o;
    o[0] = (short)f2bf(v0.x); o[1] = (short)f2bf(v0.y);
    o[2] = (short)f2bf(v0.z); o[3] = (short)f2bf(v0.w);
    o[4] = (short)f2bf(v1.x); o[5] = (short)f2bf(v1.y);
    o[6] = (short)f2bf(v1.z); o[7] = (short)f2bf(v1.w);
    *(short8v*)(embb + (size_t)t * 8) = o;
}

// ---------------------------------------------------------------------------
// WTf: fragment-ready bf16 repack of [Ul;Ur;Wx] (K=768, N=1280) for MFMA B.
// short8 index = (ng*24 + ks)*64 + lane ; lane = q*16 + c
//   holds B[k = ks*32 + q*8 + j][col = ng*16 + c],  j = 0..7
// ---------------------------------------------------------------------------
__global__ __launch_bounds__(256) void prep_wtf(
    const float* __restrict__ Ul, const float* __restrict__ Ur,
    const float* __restrict__ Wx, unsigned short* __restrict__ WTf)
{
    const int t = blockIdx.x * 256 + threadIdx.x;   // 0..122879
    const int l = t & 63;
    const int q = l >> 4, c = l & 15;
    const int ks = (t >> 6) % 24;
    const int ng = t / (24 * 64);                    // 0..79
    const int col = ng * 16 + c;
    const int k = ks * 32 + q * 8;
    const float* src = (k < 256) ? (Ul + (size_t)k * NG + col)
                     : (k < 512) ? (Ur + (size_t)(k - 256) * NG + col)
                                 : (Wx + (size_t)(k - 512) * NG + col);
    short8v v;
    #pragma unroll
    for (int j = 0; j < 8; ++j) v[j] = (short)f2bf(src[(size_t)j * NG]);
    *(short8v*)(WTf + (size_t)t * 8) = v;
}

// ---------------------------------------------------------------------------
// gemm_tab: O[2048][1280] = bf16( A(2048x256) @ Wsec(256x1280) [+ bias] ).
// Wsec = ks_base0 + 8*blockIdx.z (0=Ul, 8=Ur, 16=Wx); O = z ? O1 : O0.
// TAB=true also computes the leaf h/c tables in-epilogue from acc.
// RT=2 (32-row tiles): grid TAB 256 blocks, HU 512 -- fills the machine.
// ---------------------------------------------------------------------------
template <bool TAB, int RT>
__global__ __launch_bounds__(256, 2) void gemm_tab(
    const unsigned short* __restrict__ WTf, const unsigned short* __restrict__ A,
    const float* __restrict__ bias, unsigned short* __restrict__ O0,
    unsigned short* __restrict__ O1,
    unsigned short* __restrict__ Hleaf, unsigned short* __restrict__ Cleaf,
    const int ks_base0)
{
    constexpr int M   = RT * 16;        // rows per block
    constexpr int CPW = RT / 2 ? RT / 2 : 1;   // staging chunks per wave
    __shared__ __align__(16) unsigned short Ab[2][RT * 1024];   // dbuf: M rows x 64 k
    __shared__ __align__(16) unsigned short wbE[RT * 5120];     // 5 gates x M rows x 64 cols

    const int tid  = threadIdx.x;
    const int lane = tid & 63;
    const int w    = tid >> 6;                  // 0..3 = col-tile
    const int quad = lane >> 4, col15 = lane & 15;
    const int jt = blockIdx.x;
    const int rowBase = blockIdx.y * M;         // A row
    const int jbase   = jt * 64;
    const int ks_base = ks_base0 + (int)blockIdx.z * 8;
    unsigned short* O = blockIdx.z ? O1 : O0;

    const unsigned short* agp[CPW];
    unsigned short* ldst[CPW];
    #pragma unroll
    for (int t = 0; t < CPW; ++t) {
        const int ch = CPW * w + t, sub = ch / RT, rt = ch % RT;
        const int srow = rowBase + rt * 16 + col15;
        agp[t]  = A + (size_t)srow * HDIM + sub * 32 + quad * 8;
        ldst[t] = &Ab[0][0] + ch * 512;
    }

    const short8v* WTfv = (const short8v*)WTf;
    uint32 boff[5];
    #pragma unroll
    for (int g = 0; g < 5; ++g)
        boff[g] = (uint32)(((g * 16 + jt * 4 + w) * 24 + ks_base) * 64 + lane);

    float4v acc[RT][5];
    #pragma unroll
    for (int rt = 0; rt < RT; ++rt)
        #pragma unroll
        for (int g = 0; g < 5; ++g)
            #pragma unroll
            for (int e = 0; e < 4; ++e) acc[rt][g][e] = 0.0f;

    #pragma unroll
    for (int t = 0; t < CPW; ++t) dma16(agp[t], ldst[t]);
    __syncthreads();

    #pragma unroll
    for (int s = 0; s < 4; ++s) {
        if (s < 3) {
            #pragma unroll
            for (int t = 0; t < CPW; ++t)
                dma16(agp[t] + (s + 1) * 64, ldst[t] + ((s + 1) & 1) * (RT * 1024));
        }
        #pragma unroll
        for (int sub = 0; sub < 2; ++sub) {
            short8v bf[5];
            #pragma unroll
            for (int g = 0; g < 5; ++g) bf[g] = WTfv[boff[g] + (s * 2 + sub) * 64];
            #pragma unroll
            for (int rt = 0; rt < RT; ++rt) {
                const short8v af = *(const short8v*)&Ab[s & 1][(sub * RT + rt) * 512 + lane * 8];
                #pragma unroll
                for (int g = 0; g < 5; ++g)
                    acc[rt][g] = __builtin_amdgcn_mfma_f32_16x16x32_bf16(
                        af, bf[g], acc[rt][g], 0, 0, 0);
            }
        }
        __syncthreads();
    }

    const int jl = w * 16 + col15;
    const int j  = jbase + jl;
    float bz[5];
    #pragma unroll
    for (int g = 0; g < 5; ++g) bz[g] = bias ? bias[g * 256 + j] : 0.0f;
    const int jchunk = jl >> 3, jpos = jl & 7;

    if (TAB) {
        // Leaf h/c tables directly from acc (gi=g0, go=g3, gu=g4).
        #pragma unroll
        for (int rt = 0; rt < RT; ++rt) {
            #pragma unroll
            for (int reg = 0; reg < 4; ++reg) {
                const int rr = rt * 16 + quad * 4 + reg;
                const float gi = acc[rt][0][reg] + bz[0];
                const float go = acc[rt][3][reg] + bz[3];
                const float gu = acc[rt][4][reg] + bz[4];
                const float c = sigm(gi) * tanh_fast(gu);
                const float h = sigm(go) * tanh_fast(c);
                Hleaf[(size_t)(rowBase + rr) * HDIM + j] = f2bf(h);
                Cleaf[(size_t)(rowBase + rr) * HDIM + j] = f2bf(c);
            }
        }
    }

    #pragma unroll
    for (int rt = 0; rt < RT; ++rt) {
        #pragma unroll
        for (int reg = 0; reg < 4; ++reg) {
            const int rr = rt * 16 + quad * 4 + reg;
            const int roff = ((jchunk + 2 * quad) & 7) * 8 + jpos;  // (rr>>2)&3==quad
            #pragma unroll
            for (int g = 0; g < 5; ++g)
                wbE[(g * M + rr) * 64 + roff] = f2bf(acc[rt][g][reg] + bz[g]);
        }
    }
    __syncthreads();

    #pragma unroll
    for (int k2 = 0; k2 < RT * 5 / 2; ++k2) {       // 5*M*8/256 iterations
        const int c = tid + k2 * 256;                // short8 index
        const int g = c / (M * 8), rr = (c >> 3) & (M - 1), u = c & 7;
        const int ru = (u + 2 * ((rr >> 2) & 3)) & 7;
        const short8v v = *(const short8v*)&wbE[(g * M + rr) * 64 + ru * 8];
        *(short8v*)(O + (size_t)(rowBase + rr) * NG + g * 256 + jbase + u * 8) = v;
    }
}

// ---------------------------------------------------------------------------
// leafcell: level d=8 WITHOUT a GEMM.  gates = HUl[tokL] + HUr[tokR] +
// EWb[tokN] (bias inside EWb) -> LSTM cell with cl/cr from Cleaf.
// 2 col-octets per thread (j, j+128): 2x loads in flight per thread.
// ---------------------------------------------------------------------------
__global__ __launch_bounds__(256) void leafcell_kernel(
    const int* __restrict__ tokens,
    const unsigned short* __restrict__ HUl, const unsigned short* __restrict__ HUr,
    const unsigned short* __restrict__ EWb, const unsigned short* __restrict__ Cleaf,
    unsigned short* __restrict__ hdst, unsigned short* __restrict__ cdst)
{
    const int t = blockIdx.x * 256 + threadIdx.x;   // 0..524287
    const int row = t >> 4;                          // 0..32767 = b*256 + i
    const int j0  = (t & 15) * 8;                    // first octet; second = j0+128
    const int b = row >> 8, i = row & 255;
    const int tokN = tokens[b * NNODES + 255 + i];
    const int tokL = tokens[b * NNODES + 511 + 2 * i];
    const int tokR = tokens[b * NNODES + 512 + 2 * i];

    const unsigned short* pl = HUl + (size_t)tokL * NG + j0;
    const unsigned short* pr = HUr + (size_t)tokR * NG + j0;
    const unsigned short* pn = EWb + (size_t)tokN * NG + j0;

    float g5[5][2][8];
    #pragma unroll
    for (int g = 0; g < 5; ++g) {
        #pragma unroll
        for (int h2 = 0; h2 < 2; ++h2) {
            const short8v vl = *(const short8v*)(pl + g * 256 + h2 * 128);
            const short8v vr = *(const short8v*)(pr + g * 256 + h2 * 128);
            const short8v vn = *(const short8v*)(pn + g * 256 + h2 * 128);
            #pragma unroll
            for (int e = 0; e < 8; ++e)
                g5[g][h2][e] = bf2f((unsigned short)vl[e]) + bf2f((unsigned short)vr[e])
                             + bf2f((unsigned short)vn[e]);
        }
    }
    #pragma unroll
    for (int h2 = 0; h2 < 2; ++h2) {
        const short8v cl8 = *(const short8v*)(Cleaf + (size_t)tokL * HDIM + j0 + h2 * 128);
        const short8v cr8 = *(const short8v*)(Cleaf + (size_t)tokR * HDIM + j0 + h2 * 128);
        short8v ho, co;
        #pragma unroll
        for (int e = 0; e < 8; ++e) {
            const float ii = sigm(g5[0][h2][e]), fl = sigm(g5[1][h2][e]);
            const float fr = sigm(g5[2][h2][e]), oo = sigm(g5[3][h2][e]);
            const float uu = tanh_fast(g5[4][h2][e]);
            const float c = ii * uu + fl * bf2f((unsigned short)cl8[e])
                                    + fr * bf2f((unsigned short)cr8[e]);
            const float h = oo * tanh_fast(c);
            co[e] = (short)f2bf(c);
            ho[e] = (short)f2bf(h);
        }
        *(short8v*)(hdst + (size_t)row * HDIM + j0 + h2 * 128) = ho;
        *(short8v*)(cdst + (size_t)row * HDIM + j0 + h2 * 128) = co;
    }
}

// ---------------------------------------------------------------------------
// Levels d=7..0: K=768 fold [hl|hr|x]@[Ul;Ur;Wx].
// R16: BK 128 -> 256 (3 steps, one per operand: s=0 hl, s=1 hr, s=2 x).
// Halves the per-block vmcnt(0)+barrier drains again (R3->R4's 12->6 gave
// +8%); each step now has 160 MFMA/wave (~800-1600cy under SIMD sharing),
// fully covering the 8-chunk prefetch.  LDS dbuf 64 KB (hard cap 2
// blocks/CU; effective residency was already ~1.5-2).  acc stays 80 VGPR;
// (256,1) gives the allocator room (est ~150; spill would show as
// WRITE_SIZE inflation per R1's signature).
// SWZ=true (d=7): 1D grid swizzle -- jt-mates co-XCD AND co-resident.
// SWZ=false (d<=6): 2D grid (rowTile, jt).
// ---------------------------------------------------------------------------
template <bool SWZ>
__global__ __launch_bounds__(256, 1) void level_fold(
    const unsigned short* __restrict__ WTf, const int* __restrict__ tokens,
    const unsigned short* __restrict__ embb,
    const unsigned short* __restrict__ hsrc, const unsigned short* __restrict__ csrc,
    const float* __restrict__ bias,
    unsigned short* __restrict__ hdst, unsigned short* __restrict__ cdst,
    float* __restrict__ out, const int d)
{
    const int n = 1 << d;

    __shared__ __align__(16) unsigned short Ab[2][16384];   // 64 KB: dbuf 64r x 256k

    const int tid  = threadIdx.x;
    const int lane = tid & 63;
    const int w    = tid >> 6;
    const int quad = lane >> 4, col15 = lane & 15;

    int jt, rowTile;
    if (SWZ) {
        const int L = blockIdx.x;
        jt      = (L >> 3) & 3;
        rowTile = (L >> 5) * 8 + (L & 7);
    } else {
        jt      = blockIdx.y;
        rowTile = blockIdx.x;
    }
    const int rowBase = rowTile * 64;
    const int jbase   = jt * 64;

    // Base byte offsets per row-tile (k-sub term added at use: sub*64 bytes).
    uint32 oL[4], oN[4];
    #pragma unroll
    for (int t = 0; t < 4; ++t) {
        const int srow = rowBase + t * 16 + col15;
        const int b = srow >> d, i = srow & (n - 1);
        oN[t] = (uint32)tokens[b * NNODES + (n - 1) + i] * 512u + (uint32)(quad * 16);
        oL[t] = (uint32)(2 * srow) * 512u + (uint32)(quad * 16);
    }
    const char* hb = (const char*)hsrc;
    const char* xb = (const char*)embb;

    const short8v* WTfv = (const short8v*)WTf;
    uint32 boff[5];
    #pragma unroll
    for (int g = 0; g < 5; ++g)
        boff[g] = ((g * 16 + jt * 4 + w) * 24) * 64 + lane;   // full K=768

    const int jl = w * 16 + col15;
    const int j  = jbase + jl;
    float bz[5];
    #pragma unroll
    for (int g = 0; g < 5; ++g) bz[g] = bias[g * 256 + j];

    float4v acc[4][5];
    #pragma unroll
    for (int rt = 0; rt < 4; ++rt)
        #pragma unroll
        for (int g = 0; g < 5; ++g)
            #pragma unroll
            for (int e = 0; e < 4; ++e) acc[rt][g][e] = 0.0f;

    // Staging: per step, 32 chunks (8 k-subs x 4 row-tiles); wave w stages
    // subs {2w, 2w+1}, all 4 rts: t=0..7 -> sub = 2w + (t>>2), rt = t&3.
    // Prologue: step 0 = left-child h (k 0..255).
    {
        #pragma unroll
        for (int t = 0; t < 8; ++t) {
            const int sub = 2 * w + (t >> 2), rt = t & 3;
            dma16((const unsigned short*)(hb + oL[rt] + sub * 64),
                  &Ab[0][0] + (sub * 4 + rt) * 512);
        }
    }
    __syncthreads();

    #pragma unroll
    for (int s = 0; s < 3; ++s) {
        if (s < 2) {
            unsigned short* dstb = &Ab[(s + 1) & 1][0];
            #pragma unroll
            for (int t = 0; t < 8; ++t) {
                const int sub = 2 * w + (t >> 2), rt = t & 3;
                const char* p = (s == 0) ? (hb + oL[rt] + 512 + sub * 64)   // right child
                                         : (xb + oN[rt] + sub * 64);        // x = embb[tok]
                dma16((const unsigned short*)p, dstb + (sub * 4 + rt) * 512);
            }
        }
        #pragma unroll
        for (int sub = 0; sub < 8; ++sub) {
            short8v bf[5];
            #pragma unroll
            for (int g = 0; g < 5; ++g) bf[g] = WTfv[boff[g] + (s * 8 + sub) * 64];
            #pragma unroll
            for (int rt = 0; rt < 4; ++rt) {
                const short8v af = *(const short8v*)&Ab[s & 1][(sub * 4 + rt) * 512 + lane * 8];
                #pragma unroll
                for (int g = 0; g < 5; ++g)
                    acc[rt][g] = __builtin_amdgcn_mfma_f32_16x16x32_bf16(
                        af, bf[g], acc[rt][g], 0, 0, 0);
            }
        }
        __syncthreads();
    }

    float hv[4][4], cv[4][4];
    #pragma unroll
    for (int rt = 0; rt < 4; ++rt) {
        #pragma unroll
        for (int reg = 0; reg < 4; ++reg) {
            const int rr = rt * 16 + quad * 4 + reg;
            const int grow = rowBase + rr;
            const float cl = bf2f(csrc[(size_t)(2 * grow) * HDIM + j]);
            const float cr = bf2f(csrc[(size_t)(2 * grow + 1) * HDIM + j]);
            const float gi  = acc[rt][0][reg] + bz[0];
            const float gfl = acc[rt][1][reg] + bz[1];
            const float gfr = acc[rt][2][reg] + bz[2];
            const float go  = acc[rt][3][reg] + bz[3];
            const float gu  = acc[rt][4][reg] + bz[4];
            const float ii = sigm(gi), fl = sigm(gfl), fr = sigm(gfr), oo = sigm(go);
            const float uu = tanh_fast(gu);
            const float c = ii * uu + fl * cl + fr * cr;
            const float h = oo * tanh_fast(c);
            cv[rt][reg] = c; hv[rt][reg] = h;
            if (d == 0) out[(size_t)grow * HDIM + j] = h;  // n==1 -> b=row
        }
    }
    if (d == 0) return;   // root level: nothing reads hdst/cdst

    unsigned short* wb = &Ab[0][0];
    const int jchunk = jl >> 3, jpos = jl & 7;
    #pragma unroll
    for (int rt = 0; rt < 4; ++rt) {
        #pragma unroll
        for (int reg = 0; reg < 4; ++reg) {
            const int rr = rt * 16 + quad * 4 + reg;
            const int roff = ((jchunk + 2 * quad) & 7) * 8 + jpos;
            wb[rr * 64 + roff]        = f2bf(hv[rt][reg]);
            wb[4096 + rr * 64 + roff] = f2bf(cv[rt][reg]);
        }
    }
    __syncthreads();
    #pragma unroll
    for (int k2 = 0; k2 < 4; ++k2) {
        const int c = tid + k2 * 256;
        const int arr = c >> 9, rr = (c >> 3) & 63, u = c & 7;
        const int ru = (u + 2 * ((rr >> 2) & 3)) & 7;
        const short8v v = *(const short8v*)(wb + (arr * 4096 + rr * 64 + ru * 8));
        unsigned short* dstp = (arr ? cdst : hdst) +
            (size_t)(rowBase + rr) * HDIM + jbase + u * 8;
        *(short8v*)dstp = v;
    }
}

// ---------------------------------------------------------------------------
extern "C" void kernel_launch(void* const* d_in, const int* in_sizes, int n_in,
                              void* d_out, int out_size, void* d_ws, size_t ws_size,
                              hipStream_t stream)
{
    const int*   tokens = (const int*)d_in[0];
    const float* emb    = (const float*)d_in[1];
    const float* Wx     = (const float*)d_in[2];
    const float* Ul     = (const float*)d_in[3];
    const float* Ur     = (const float*)d_in[4];
    const float* bias   = (const float*)d_in[5];
    float* out = (float*)d_out;

    // Workspace (bf16): EWb 5.24 | HUl 5.24 | HUr 5.24 | embb 1.05 | WTf 1.97
    // | Hleaf+Cleaf 2.1 | hA,cA 2x8.4 | hB,cB 2x16.8  -> ~70 MB total.
    const size_t EW_ELEMS  = (size_t)VOCAB * NG;          // also HUl/HUr size
    const size_t EMB_ELEMS = (size_t)VOCAB * HDIM;
    const size_t WTF_ELEMS = (size_t)80 * 24 * 64 * 8;
    const size_t LT_ELEMS  = (size_t)VOCAB * HDIM;        // each of Hleaf, Cleaf
    const size_t SLOT_A    = (size_t)16384 * HDIM;        // d=7,5,3,1 outputs
    const size_t SLOT_B    = (size_t)32768 * HDIM;        // d=8,6,4,2,0 outputs
    const size_t REQUIRED  = (3 * EW_ELEMS + EMB_ELEMS + WTF_ELEMS + 2 * LT_ELEMS
                              + 2 * (SLOT_A + SLOT_B)) * 2;
    if (ws_size < REQUIRED || d_ws == nullptr) return;   // clean fail, not a fault

    char* ws = (char*)d_ws;
    unsigned short* EWb   = (unsigned short*)ws;
    unsigned short* HUl   = EWb + EW_ELEMS;
    unsigned short* HUr   = HUl + EW_ELEMS;
    unsigned short* embb  = HUr + EW_ELEMS;
    unsigned short* WTf   = embb + EMB_ELEMS;
    unsigned short* Hleaf = WTf + WTF_ELEMS;
    unsigned short* Cleaf = Hleaf + LT_ELEMS;
    unsigned short* hA    = Cleaf + LT_ELEMS;
    unsigned short* cA    = hA + SLOT_A;
    unsigned short* hB    = cA + SLOT_A;
    unsigned short* cB    = hB + SLOT_B;

    embb_kernel<<<dim3(256), 256, 0, stream>>>(emb, embb);
    prep_wtf<<<dim3(480), 256, 0, stream>>>(Ul, Ur, Wx, WTf);
    // EWb = x@Wx + b, leaf h/c tables fused; 32-row tiles -> 256 blocks.
    gemm_tab<true, 2><<<dim3(4, 64, 1), 256, 0, stream>>>(
        WTf, embb, bias, EWb, nullptr, Hleaf, Cleaf, 16);
    // HUl = Hleaf@Ul and HUr = Hleaf@Ur in ONE launch; 512 blocks.
    gemm_tab<false, 2><<<dim3(4, 64, 2), 256, 0, stream>>>(
        WTf, Hleaf, nullptr, HUl, HUr, nullptr, nullptr, 0);

    // Level d=8: pure table gather + cell (no GEMM).  Writes B-slot.
    leafcell_kernel<<<dim3(2048), 256, 0, stream>>>(
        tokens, HUl, HUr, EWb, Cleaf, hB, cB);

    // d=7: swizzle variant (1D grid).
    level_fold<true><<<dim3(4 * 256), 256, 0, stream>>>(
        WTf, tokens, embb, hB, cB, bias, hA, cA, out, 7);

    // d=6..0: 2D rows-fastest variant.
    for (int d = 6; d >= 0; --d) {
        const int NRB = 2 << d;
        const bool evenD = ((d & 1) == 0);
        const unsigned short* hs = evenD ? hA : hB;
        const unsigned short* cs = evenD ? cA : cB;
        unsigned short* hd = evenD ? hB : hA;
        unsigned short* cd = evenD ? cB : cA;
        level_fold<false><<<dim3(NRB, 4), 256, 0, stream>>>(
            WTf, tokens, embb, hs, cs, bias, hd, cd, out, d);
    }
}